// Round 1
// baseline (233.965 us; speedup 1.0000x reference)
//
#include <hip/hip_runtime.h>

#define NCLS   80
#define CH     85            // 5 + NUM_CLASSES
#define NA     3
#define BSZ    16
#define MAXB   32
#define G0     13
#define G1     26
#define G2     52
#define CELLS0 (BSZ*NA*G0*G0)            // 8112
#define CELLS1 (BSZ*NA*G1*G1)            // 32448
#define CELLS2 (BSZ*NA*G2*G2)            // 129792
#define TOTAL  (CELLS0+CELLS1+CELLS2)    // 170352

// anchors[layer][a][0]=w, [1]=h  (ANCHOR_MASK applied: [[6,7,8],[3,4,5],[0,1,2]])
__device__ const float d_anch[3][3][2] = {
  {{116.f, 90.f}, {156.f, 198.f}, {373.f, 326.f}},
  {{ 30.f, 61.f}, { 62.f,  45.f}, { 59.f, 119.f}},
  {{ 10.f, 13.f}, { 16.f,  30.f}, { 33.f,  23.f}},
};

__device__ inline float sp(float x) {          // softplus, stable
  return fmaxf(x, 0.0f) + log1pf(expf(-fabsf(x)));
}
__device__ inline float sigm(float x) {
  return 1.0f / (1.0f + expf(-x));
}
__device__ inline float wred(float v) {
  #pragma unroll
  for (int off = 32; off > 0; off >>= 1) v += __shfl_down(v, off, 64);
  return v;
}

// decode global cell id -> (layer, g, b, a, cell)
__device__ inline void decode(int t, int& l, int& g, int& b, int& a, int& cell) {
  int idx;
  if (t < CELLS0)               { l = 0; g = G0; idx = t; }
  else if (t < CELLS0 + CELLS1) { l = 1; g = G1; idx = t - CELLS0; }
  else                          { l = 2; g = G2; idx = t - CELLS0 - CELLS1; }
  int gg = g * g;
  cell = idx % gg;
  int rest = idx / gg;          // b*NA + a  (cell fastest -> coalesced feats)
  a = rest % NA;
  b = rest / NA;
}

__global__ __launch_bounds__(256)
void gather_boxes(const float* __restrict__ y0, const float* __restrict__ y1,
                  const float* __restrict__ y2, int* __restrict__ cnt,
                  float* __restrict__ boxes) {
  int t = blockIdx.x * blockDim.x + threadIdx.x;
  if (t >= TOTAL) return;
  int l, g, b, a, cell;
  decode(t, l, g, b, a, cell);
  const float* yt = (l == 0) ? y0 : (l == 1) ? y1 : y2;
  int gg = g * g;
  int base = ((b * gg + cell) * NA + a) * CH;
  float obj = yt[base + 4];
  if (obj > 0.5f) {
    int p = atomicAdd(&cnt[l * BSZ + b], 1);
    if (p < MAXB) {
      float4* dst = (float4*)(boxes + ((l * BSZ + b) * MAXB + p) * 4);
      *dst = make_float4(yt[base + 0], yt[base + 1], yt[base + 2], yt[base + 3]);
    }
  }
}

__global__ __launch_bounds__(256)
void yolo_loss_main(const float* __restrict__ f0, const float* __restrict__ f1,
                    const float* __restrict__ f2, const float* __restrict__ y0,
                    const float* __restrict__ y1, const float* __restrict__ y2,
                    const int* __restrict__ cnt, const float* __restrict__ boxes,
                    float* __restrict__ acc) {
  int t = blockIdx.x * blockDim.x + threadIdx.x;
  float vxy = 0.f, vwh = 0.f, vconf = 0.f, vcls = 0.f;
  if (t < TOTAL) {
    int l, g, b, a, cell;
    decode(t, l, g, b, a, cell);
    const float* fp = (l == 0) ? f0 : (l == 1) ? f1 : f2;
    const float* yp = (l == 0) ? y0 : (l == 1) ? y1 : y2;
    int gg = g * g;
    int fbase = ((b * NA + a) * CH) * gg + cell;   // + c*gg per channel
    int ybase = ((b * gg + cell) * NA + a) * CH;   // + c per channel

    float t0 = fp[fbase + 0 * gg];
    float t1 = fp[fbase + 1 * gg];
    float t2 = fp[fbase + 2 * gg];
    float t3 = fp[fbase + 3 * gg];
    float t4 = fp[fbase + 4 * gg];
    float obj = yp[ybase + 4];

    int xi = cell % g, yi = cell / g;
    float inv_g = 1.0f / (float)g;
    float aw = d_anch[l][a][0], ah = d_anch[l][a][1];

    // pred box (normalized units)
    float px = (sigm(t0) + (float)xi) * inv_g;
    float py = (sigm(t1) + (float)yi) * inv_g;
    float pw = expf(t2) * aw * (1.0f / 416.0f);
    float ph = expf(t3) * ah * (1.0f / 416.0f);

    // best IoU vs this batch's true boxes
    int nb = cnt[l * BSZ + b];
    nb = nb > MAXB ? MAXB : nb;
    const float4* bxs = (const float4*)(boxes + (l * BSZ + b) * MAXB * 4);
    float pminx = px - pw * 0.5f, pmaxx = px + pw * 0.5f;
    float pminy = py - ph * 0.5f, pmaxy = py + ph * 0.5f;
    float pa = pw * ph;
    float best = 0.0f;
    for (int j = 0; j < nb; ++j) {
      float4 tb = bxs[j];
      float iw = fminf(pmaxx, tb.x + tb.z * 0.5f) - fmaxf(pminx, tb.x - tb.z * 0.5f);
      float ih = fminf(pmaxy, tb.y + tb.w * 0.5f) - fmaxf(pminy, tb.y - tb.w * 0.5f);
      iw = fmaxf(iw, 0.f); ih = fmaxf(ih, 0.f);
      float inter = iw * ih;
      float iou = inter / (pa + tb.z * tb.w - inter);
      best = fmaxf(best, iou);
    }
    float ignore = best < 0.5f ? 1.0f : 0.0f;

    float bce4 = sp(t4) - t4 * obj;
    vconf = bce4 * (obj + (1.0f - obj) * ignore);

    if (obj > 0.0f) {
      float ytx = yp[ybase + 0], yty = yp[ybase + 1];
      float ytw = yp[ybase + 2], yth = yp[ybase + 3];
      float rtx = ytx * (float)g - (float)xi;
      float rty = yty * (float)g - (float)yi;
      float scale = 2.0f - ytw * yth;
      vxy = obj * scale * ((sp(t0) - t0 * rtx) + (sp(t1) - t1 * rty));
      float rtw = logf(ytw * 416.0f / aw);
      float rth = logf(yth * 416.0f / ah);
      vwh = obj * scale * ((t2 - rtw) * (t2 - rtw) + (t3 - rth) * (t3 - rth));
      float cl = 0.f;
      for (int c = 0; c < NCLS; ++c) {
        float lg = fp[fbase + (5 + c) * gg];
        float tt = yp[ybase + 5 + c];
        cl += sp(lg) - lg * tt;
      }
      vcls = obj * cl;
    }
  }

  // block reduction: wave shuffle -> LDS -> 4 atomics per block
  __shared__ float sm[4][4];
  int lane = threadIdx.x & 63, wv = threadIdx.x >> 6;
  vxy = wred(vxy); vwh = wred(vwh); vconf = wred(vconf); vcls = wred(vcls);
  if (lane == 0) { sm[0][wv] = vxy; sm[1][wv] = vwh; sm[2][wv] = vconf; sm[3][wv] = vcls; }
  __syncthreads();
  if (threadIdx.x < 4) {
    float s = sm[threadIdx.x][0] + sm[threadIdx.x][1] + sm[threadIdx.x][2] + sm[threadIdx.x][3];
    atomicAdd(&acc[threadIdx.x], s);
  }
}

__global__ void finalize(const float* __restrict__ acc, float* __restrict__ out) {
  float xy = acc[0] * (1.0f / BSZ);
  float wh = acc[1] * (1.0f / BSZ);
  float cf = acc[2] * (1.0f / BSZ);
  float cl = acc[3] * (1.0f / BSZ);
  out[0] = xy + wh + cf + cl;
  out[1] = xy; out[2] = wh; out[3] = cf; out[4] = cl;
}

extern "C" void kernel_launch(void* const* d_in, const int* in_sizes, int n_in,
                              void* d_out, int out_size, void* d_ws, size_t ws_size,
                              hipStream_t stream) {
  // setup_inputs() dict order: feats0, ytrue0, feats1, ytrue1, feats2, ytrue2
  const float* f0 = (const float*)d_in[0];
  const float* y0 = (const float*)d_in[1];
  const float* f1 = (const float*)d_in[2];
  const float* y1 = (const float*)d_in[3];
  const float* f2 = (const float*)d_in[4];
  const float* y2 = (const float*)d_in[5];

  float* acc   = (float*)d_ws;                        // 4 floats
  int*   cnt   = (int*)((char*)d_ws + 64);            // 48 ints
  float* boxes = (float*)((char*)d_ws + 256);         // 48*32*4 floats

  hipMemsetAsync(d_ws, 0, 256, stream);               // zero acc + cnt

  int threads = 256;
  int blocks = (TOTAL + threads - 1) / threads;
  gather_boxes<<<blocks, threads, 0, stream>>>(y0, y1, y2, cnt, boxes);
  yolo_loss_main<<<blocks, threads, 0, stream>>>(f0, f1, f2, y0, y1, y2, cnt, boxes, acc);
  finalize<<<1, 1, 0, stream>>>(acc, (float*)d_out);
}

// Round 2
// 167.244 us; speedup vs baseline: 1.3989x; 1.3989x over previous
//
#include <hip/hip_runtime.h>

#define NCLS 80
#define REC  255            // 3*85 floats per (b,cell) record in ytrue
#define NA   3
#define BSZ  16
#define MAXB 32

#define G0 13
#define G1 26
#define G2 52
#define GG0 (G0*G0)
#define GG1 (G1*G1)
#define GG2 (G2*G2)
#define CELLS0 (BSZ*NA*GG0)
#define CELLS1 (BSZ*NA*GG1)
#define CELLS2 (BSZ*NA*GG2)
#define TOTAL  (CELLS0+CELLS1+CELLS2)     // 170352

#define R0 (BSZ*GG0)
#define R1 (BSZ*GG1)
#define R2 (BSZ*GG2)
#define F0 (R0*REC/4)       // float4 count per layer ytrue (all divisible by 4)
#define F1 (R1*REC/4)
#define F2 (R2*REC/4)
#define FT (F0+F1+F2)

#define MB ((TOTAL+255)/256)   // 666 main blocks
#define OB 240                 // obj-correction blocks: 4 waves each -> 960 slots

__device__ const float d_anch[3][3][2] = {
  {{116.f, 90.f}, {156.f, 198.f}, {373.f, 326.f}},
  {{ 30.f, 61.f}, { 62.f,  45.f}, { 59.f, 119.f}},
  {{ 10.f, 13.f}, { 16.f,  30.f}, { 33.f,  23.f}},
};

__device__ inline float sp(float x) {          // softplus, stable
  return fmaxf(x, 0.0f) + log1pf(expf(-fabsf(x)));
}
__device__ inline float sigm(float x) { return 1.0f / (1.0f + expf(-x)); }
__device__ inline float wred(float v) {
  #pragma unroll
  for (int off = 32; off > 0; off >>= 1) v += __shfl_down(v, off, 64);
  return v;
}

// ---------------- kernel 1: coalesced ytrue scan -> boxes + obj list --------
template<int L>
__device__ inline void scan4(int q, const float* __restrict__ yt,
                             int* __restrict__ cnt, float* __restrict__ boxes,
                             int* __restrict__ total, int* __restrict__ objlist) {
  constexpr int GG = (L == 0) ? GG0 : (L == 1) ? GG1 : GG2;
  float4 v = ((const float4*)yt)[q];
  float vv[4] = {v.x, v.y, v.z, v.w};
  int w0 = q * 4;
  #pragma unroll
  for (int k = 0; k < 4; ++k) {
    int w = w0 + k;
    unsigned rec = (unsigned)w / 255u;          // const divisor -> magic mul
    int o = w - (int)rec * 255;
    if (o == 4 || o == 89 || o == 174) {
      float obj = vv[k];
      if (obj > 0.5f) {
        int a = (o == 89) ? 1 : (o == 174) ? 2 : 0;
        unsigned b = rec / (unsigned)GG;        // const divisor
        int cell = (int)(rec - b * (unsigned)GG);
        int grp = L * BSZ + (int)b;
        int p = atomicAdd(&cnt[grp], 1);
        if (p < MAXB) {
          const float* rb = yt + (size_t)rec * REC + a * 85;
          float* d = boxes + (grp * MAXB + p) * 4;
          d[0] = rb[0]; d[1] = rb[1]; d[2] = rb[2]; d[3] = rb[3];
        }
        int s = atomicAdd(total, 1);
        if (s < 1024) objlist[s] = (grp << 18) | (a << 16) | cell;
      }
    }
  }
}

__global__ __launch_bounds__(256)
void scan_kernel(const float* __restrict__ y0, const float* __restrict__ y1,
                 const float* __restrict__ y2, int* __restrict__ cnt,
                 float* __restrict__ boxes, int* __restrict__ total,
                 int* __restrict__ objlist) {
  int nth = gridDim.x * blockDim.x;
  for (int q = blockIdx.x * blockDim.x + threadIdx.x; q < FT; q += nth) {
    if (q < F0)           scan4<0>(q,           y0, cnt, boxes, total, objlist);
    else if (q < F0 + F1) scan4<1>(q - F0,      y1, cnt, boxes, total, objlist);
    else                  scan4<2>(q - F0 - F1, y2, cnt, boxes, total, objlist);
  }
}

// ---------------- kernel 2: losses (main conf + obj corrections + finalize) -
__device__ inline float best_iou(float px, float py, float pw, float ph,
                                 const float* __restrict__ boxes, int grp, int nb) {
  float pminx = px - pw * 0.5f, pmaxx = px + pw * 0.5f;
  float pminy = py - ph * 0.5f, pmaxy = py + ph * 0.5f;
  float pa = pw * ph;
  const float4* bxs = (const float4*)(boxes + grp * MAXB * 4);
  float best = 0.0f;
  for (int j = 0; j < nb; ++j) {
    float4 tb = bxs[j];
    float iw = fminf(pmaxx, tb.x + tb.z * 0.5f) - fmaxf(pminx, tb.x - tb.z * 0.5f);
    float ih = fminf(pmaxy, tb.y + tb.w * 0.5f) - fmaxf(pminy, tb.y - tb.w * 0.5f);
    iw = fmaxf(iw, 0.f); ih = fmaxf(ih, 0.f);
    float inter = iw * ih;
    best = fmaxf(best, inter / (pa + tb.z * tb.w - inter));
  }
  return best;
}

template<int L>
__device__ inline float conf_cell(int idx, const float* __restrict__ fp,
                                  const int* __restrict__ cnt,
                                  const float* __restrict__ boxes) {
  constexpr int GG = (L == 0) ? GG0 : (L == 1) ? GG1 : GG2;
  constexpr int G  = (L == 0) ? G0  : (L == 1) ? G1  : G2;
  unsigned rest = (unsigned)idx / (unsigned)GG;       // const divisors
  int cell = idx - (int)rest * GG;
  unsigned b = rest / 3u;
  int a = (int)(rest - b * 3u);
  int fbase = ((int)(b * 3u) + a) * 85 * GG + cell;
  float t0 = fp[fbase];
  float t1 = fp[fbase + GG];
  float t2 = fp[fbase + 2 * GG];
  float t3 = fp[fbase + 3 * GG];
  float t4 = fp[fbase + 4 * GG];
  unsigned yi = (unsigned)cell / (unsigned)G;
  int xi = cell - (int)yi * G;
  float inv_g = 1.0f / (float)G;
  float aw = d_anch[L][a][0], ah = d_anch[L][a][1];
  float px = (sigm(t0) + (float)xi) * inv_g;
  float py = (sigm(t1) + (float)yi) * inv_g;
  float pw = expf(t2) * aw * (1.0f / 416.0f);
  float ph = expf(t3) * ah * (1.0f / 416.0f);
  int grp = L * BSZ + (int)b;
  int nb = cnt[grp]; nb = nb > MAXB ? MAXB : nb;
  float best = best_iou(px, py, pw, ph, boxes, grp, nb);
  return sp(t4) * (best < 0.5f ? 1.0f : 0.0f);        // obj treated as 0 here
}

__global__ __launch_bounds__(256)
void loss_kernel(const float* __restrict__ f0, const float* __restrict__ f1,
                 const float* __restrict__ f2, const float* __restrict__ y0,
                 const float* __restrict__ y1, const float* __restrict__ y2,
                 const int* __restrict__ cnt, const float* __restrict__ boxes,
                 const int* __restrict__ total, const int* __restrict__ objlist,
                 float* __restrict__ acc, int* __restrict__ done,
                 float* __restrict__ out) {
  float vxy = 0.f, vwh = 0.f, vconf = 0.f, vcls = 0.f;
  int lane = threadIdx.x & 63, wv = threadIdx.x >> 6;

  if (blockIdx.x < MB) {
    int t = blockIdx.x * 256 + threadIdx.x;
    if (t < TOTAL) {
      if (t < CELLS0)                vconf = conf_cell<0>(t,                  f0, cnt, boxes);
      else if (t < CELLS0 + CELLS1)  vconf = conf_cell<1>(t - CELLS0,         f1, cnt, boxes);
      else                           vconf = conf_cell<2>(t - CELLS0 - CELLS1, f2, cnt, boxes);
    }
  } else {
    // obj-correction path: one wave per obj cell
    int e = (blockIdx.x - MB) * 4 + wv;
    int tot = *total; if (tot > 1024) tot = 1024;
    if (e < tot) {
      int pk = objlist[e];
      int grp = pk >> 18, a = (pk >> 16) & 3, cell = pk & 0xFFFF;
      int l = grp >> 4, b = grp & 15;
      int GGv, Gv;
      const float *fp, *yp;
      if (l == 0)      { GGv = GG0; Gv = G0; fp = f0; yp = y0; }
      else if (l == 1) { GGv = GG1; Gv = G1; fp = f1; yp = y1; }
      else             { GGv = GG2; Gv = G2; fp = f2; yp = y2; }
      int rec   = b * GGv + cell;
      int ybase = rec * REC + a * 85;
      int fbase = (b * NA + a) * 85 * GGv + cell;
      float objv = yp[ybase + 4];               // broadcast load (==1.0)

      // lane-parallel class BCE: lane c covers class c, lanes 0..15 also c+64
      {
        float lg = fp[fbase + (5 + lane) * GGv];
        vcls = sp(lg) - lg * yp[ybase + 5 + lane];
        if (lane < 16) {
          int c2 = lane + 64;
          float lg2 = fp[fbase + (5 + c2) * GGv];
          vcls += sp(lg2) - lg2 * yp[ybase + 5 + c2];
        }
        vcls *= objv;
      }

      if (lane == 0) {
        float t0 = fp[fbase];
        float t1 = fp[fbase + GGv];
        float t2 = fp[fbase + 2 * GGv];
        float t3 = fp[fbase + 3 * GGv];
        float t4 = fp[fbase + 4 * GGv];
        float ytx = yp[ybase], yty = yp[ybase + 1];
        float ytw = yp[ybase + 2], yth = yp[ybase + 3];
        int yi = cell / Gv, xi = cell - yi * Gv;
        float aw = d_anch[l][a][0], ah = d_anch[l][a][1];
        float rtx = ytx * (float)Gv - (float)xi;
        float rty = yty * (float)Gv - (float)yi;
        float scale = 2.0f - ytw * yth;
        vxy = objv * scale * ((sp(t0) - t0 * rtx) + (sp(t1) - t1 * rty));
        float rtw = logf(ytw * 416.0f / aw);
        float rth = logf(yth * 416.0f / ah);
        vwh = objv * scale * ((t2 - rtw) * (t2 - rtw) + (t3 - rth) * (t3 - rth));
        // conf correction: main pass added sp(t4)*ignore (obj=0 form);
        // true contribution is (sp(t4)-t4*obj)*(obj+(1-obj)*ignore)
        float px = (sigm(t0) + (float)xi) / (float)Gv;
        float py = (sigm(t1) + (float)yi) / (float)Gv;
        float pw = expf(t2) * aw * (1.0f / 416.0f);
        float ph = expf(t3) * ah * (1.0f / 416.0f);
        int nb = cnt[grp]; nb = nb > MAXB ? MAXB : nb;
        float best = best_iou(px, py, pw, ph, boxes, grp, nb);
        float ign = best < 0.5f ? 1.0f : 0.0f;
        float spt4 = sp(t4);
        float bce4 = spt4 - t4 * objv;
        vconf = bce4 * (objv + (1.0f - objv) * ign) - spt4 * ign;
      }
    }
  }

  // block reduction: wave shuffle -> LDS -> 4 atomics per block
  __shared__ float sm[4][4];
  vxy = wred(vxy); vwh = wred(vwh); vconf = wred(vconf); vcls = wred(vcls);
  if (lane == 0) { sm[0][wv] = vxy; sm[1][wv] = vwh; sm[2][wv] = vconf; sm[3][wv] = vcls; }
  __syncthreads();
  if (threadIdx.x < 4) {
    float s = sm[threadIdx.x][0] + sm[threadIdx.x][1] + sm[threadIdx.x][2] + sm[threadIdx.x][3];
    atomicAdd(&acc[threadIdx.x], s);
  }
  __syncthreads();

  // last block finalizes
  if (threadIdx.x == 0) {
    __threadfence();
    int d = atomicAdd(done, 1);
    if (d == (int)gridDim.x - 1) {
      float xy = atomicAdd(&acc[0], 0.0f) * (1.0f / BSZ);
      float wh = atomicAdd(&acc[1], 0.0f) * (1.0f / BSZ);
      float cf = atomicAdd(&acc[2], 0.0f) * (1.0f / BSZ);
      float cl = atomicAdd(&acc[3], 0.0f) * (1.0f / BSZ);
      out[0] = xy + wh + cf + cl;
      out[1] = xy; out[2] = wh; out[3] = cf; out[4] = cl;
    }
  }
}

extern "C" void kernel_launch(void* const* d_in, const int* in_sizes, int n_in,
                              void* d_out, int out_size, void* d_ws, size_t ws_size,
                              hipStream_t stream) {
  // setup_inputs() dict order: feats0, ytrue0, feats1, ytrue1, feats2, ytrue2
  const float* f0 = (const float*)d_in[0];
  const float* y0 = (const float*)d_in[1];
  const float* f1 = (const float*)d_in[2];
  const float* y1 = (const float*)d_in[3];
  const float* f2 = (const float*)d_in[4];
  const float* y2 = (const float*)d_in[5];

  float* acc     = (float*)d_ws;                       // 4 floats @ 0
  int*   cnt     = (int*)((char*)d_ws + 64);           // 48 ints
  int*   total   = (int*)((char*)d_ws + 256);          // 1 int
  int*   done    = (int*)((char*)d_ws + 260);          // 1 int
  int*   objlist = (int*)((char*)d_ws + 512);          // 1024 ints
  float* boxes   = (float*)((char*)d_ws + 8192);       // 48*32*4 floats

  hipMemsetAsync(d_ws, 0, 512, stream);                // acc+cnt+total+done

  scan_kernel<<<2048, 256, 0, stream>>>(y0, y1, y2, cnt, boxes, total, objlist);
  loss_kernel<<<MB + OB, 256, 0, stream>>>(f0, f1, f2, y0, y1, y2,
                                           cnt, boxes, total, objlist,
                                           acc, done, (float*)d_out);
}